// Round 2
// baseline (425.401 us; speedup 1.0000x reference)
//
#include <hip/hip_runtime.h>
#include <hip/hip_bf16.h>

#define SEQ    4096
#define SCALE  0.125f

typedef __attribute__((ext_vector_type(8))) short s8v;
typedef __attribute__((ext_vector_type(4))) float f4v;

__device__ __forceinline__ unsigned short f2bf(float f){
  unsigned int u = __builtin_bit_cast(unsigned int, f);
  u += 0x7FFFu + ((u >> 16) & 1u);
  return (unsigned short)(u >> 16);
}
__device__ __forceinline__ float bf2f(unsigned short s){
  unsigned int u = ((unsigned int)s) << 16;
  return __builtin_bit_cast(float, u);
}

typedef const __attribute__((address_space(1))) unsigned int gl_uint;
typedef __attribute__((address_space(3))) unsigned int lds_uint;

__device__ __forceinline__ void gload_lds16(const unsigned short* g, unsigned short* l){
  __builtin_amdgcn_global_load_lds((gl_uint*)g, (lds_uint*)l, 16, 0, 0);
}

// ---------------- qkv GEMM: [16384,1024]bf16 x [3072,1024]^T bf16.
// cols 0..1023   -> qt[bh][d][n] bf16 (head-transposed)
// cols 1024..2047-> kt[bh][e][n] bf16
// cols 2048..3071-> vb[row][col-2048] bf16
__global__ __launch_bounds__(256) void qkv_gemm(
    const unsigned short* __restrict__ A,
    const unsigned short* __restrict__ Bt,
    unsigned short* __restrict__ qt,
    unsigned short* __restrict__ kt,
    unsigned short* __restrict__ vb)
{
  __shared__ unsigned short sA[128*32];
  __shared__ unsigned short sB[128*32];
  const int K = 1024;
  const int tid  = threadIdx.x;
  const int wave = tid >> 6, lane = tid & 63;
  const int quad = lane >> 4, l16 = lane & 15;
  const int bm = blockIdx.y * 128, bn = blockIdx.x * 128;
  const int wm = (wave >> 1) * 64, wn = (wave & 1) * 64;

  f4v acc[4][4];
#pragma unroll
  for (int i = 0; i < 4; i++)
#pragma unroll
    for (int j = 0; j < 4; j++) acc[i][j] = (f4v){0.f,0.f,0.f,0.f};

  const unsigned short* ap = A  + (size_t)(bm + (tid >> 2)) * K + (tid & 3) * 8;
  const unsigned short* bp = Bt + (size_t)(bn + (tid >> 2)) * K + (tid & 3) * 8;
  unsigned short* sAw = sA + wave * 512;
  unsigned short* sBw = sB + wave * 512;

  for (int k0 = 0; k0 < K; k0 += 32){
    __syncthreads();
    gload_lds16(ap + k0,                    sAw);
    gload_lds16(ap + (size_t)64 * K + k0,   sAw + 2048);
    gload_lds16(bp + k0,                    sBw);
    gload_lds16(bp + (size_t)64 * K + k0,   sBw + 2048);
    __syncthreads();
    s8v af[4], bf[4];
#pragma unroll
    for (int mt = 0; mt < 4; mt++) af[mt] = *(const s8v*)&sA[(wm + mt*16 + l16)*32 + quad*8];
#pragma unroll
    for (int nt = 0; nt < 4; nt++) bf[nt] = *(const s8v*)&sB[(wn + nt*16 + l16)*32 + quad*8];
#pragma unroll
    for (int mt = 0; mt < 4; mt++)
#pragma unroll
      for (int nt = 0; nt < 4; nt++)
        acc[mt][nt] = __builtin_amdgcn_mfma_f32_16x16x32_bf16(af[mt], bf[nt], acc[mt][nt], 0, 0, 0);
  }

#pragma unroll
  for (int nt = 0; nt < 4; nt++){
    int col = bn + wn + nt*16 + l16;
    int sec = col >> 10;              // 0=q 1=k 2=v (uniform per nt tile)
    if (sec == 2){
      int vc = col - 2048;
#pragma unroll
      for (int mt = 0; mt < 4; mt++){
        int row = bm + wm + mt*16 + quad*4;
#pragma unroll
        for (int r = 0; r < 4; r++)
          vb[(size_t)(row + r) * 1024 + vc] = f2bf(acc[mt][nt][r]);
      }
    } else {
      unsigned short* dst = sec ? kt : qt;
      int h = (col >> 6) & 15;
      int de = col & 63;
#pragma unroll
      for (int mt = 0; mt < 4; mt++){
        int row = bm + wm + mt*16 + quad*4;  // multiple of 4
        int bb = row >> 12;
        int nl = row & 4095;
        ushort4 o;
        o.x = f2bf(acc[mt][nt][0]); o.y = f2bf(acc[mt][nt][1]);
        o.z = f2bf(acc[mt][nt][2]); o.w = f2bf(acc[mt][nt][3]);
        *(ushort4*)&dst[(((size_t)bb * 16 + h) * 64 + de) * SEQ + nl] = o;
      }
    }
  }
}

// ---------------- final GEMM: out = A[M,K] * Bt[N,K]^T + bias, fp32 out
__global__ __launch_bounds__(256) void gemm_bt(
    const unsigned short* __restrict__ A,
    const unsigned short* __restrict__ Bt,
    float* __restrict__ Cf,
    const float* __restrict__ bias,
    int M, int N, int K)
{
  __shared__ unsigned short sA[128*32];
  __shared__ unsigned short sB[128*32];
  const int tid  = threadIdx.x;
  const int wave = tid >> 6, lane = tid & 63;
  const int quad = lane >> 4, l16 = lane & 15;
  const int bm = blockIdx.y * 128, bn = blockIdx.x * 128;
  const int wm = (wave >> 1) * 64, wn = (wave & 1) * 64;

  f4v acc[4][4];
#pragma unroll
  for (int i = 0; i < 4; i++)
#pragma unroll
    for (int j = 0; j < 4; j++) acc[i][j] = (f4v){0.f,0.f,0.f,0.f};

  const unsigned short* ap = A  + (size_t)(bm + (tid >> 2)) * K + (tid & 3) * 8;
  const unsigned short* bp = Bt + (size_t)(bn + (tid >> 2)) * K + (tid & 3) * 8;
  unsigned short* sAw = sA + wave * 512;
  unsigned short* sBw = sB + wave * 512;

  for (int k0 = 0; k0 < K; k0 += 32){
    __syncthreads();
    gload_lds16(ap + k0,                    sAw);
    gload_lds16(ap + (size_t)64 * K + k0,   sAw + 2048);
    gload_lds16(bp + k0,                    sBw);
    gload_lds16(bp + (size_t)64 * K + k0,   sBw + 2048);
    __syncthreads();
    s8v af[4], bf[4];
#pragma unroll
    for (int mt = 0; mt < 4; mt++) af[mt] = *(const s8v*)&sA[(wm + mt*16 + l16)*32 + quad*8];
#pragma unroll
    for (int nt = 0; nt < 4; nt++) bf[nt] = *(const s8v*)&sB[(wn + nt*16 + l16)*32 + quad*8];
#pragma unroll
    for (int mt = 0; mt < 4; mt++)
#pragma unroll
      for (int nt = 0; nt < 4; nt++)
        acc[mt][nt] = __builtin_amdgcn_mfma_f32_16x16x32_bf16(af[mt], bf[nt], acc[mt][nt], 0, 0, 0);
  }

#pragma unroll
  for (int nt = 0; nt < 4; nt++){
    int col = bn + wn + nt*16 + l16;
    float bv = bias[col];
#pragma unroll
    for (int mt = 0; mt < 4; mt++){
      int row = bm + wm + mt*16 + quad*4;
#pragma unroll
      for (int r = 0; r < 4; r++)
        Cf[(size_t)(row + r) * 1024 + col] = acc[mt][nt][r] + bv;
    }
  }
}

// ---------------- fp32 -> bf16 elementwise (4/thread)
__global__ void cvt_f32_bf16(const float4* __restrict__ in, ushort4* __restrict__ outp){
  int i = blockIdx.x * 256 + threadIdx.x;
  float4 v = in[i];
  ushort4 o;
  o.x = f2bf(v.x); o.y = f2bf(v.y); o.z = f2bf(v.z); o.w = f2bf(v.w);
  outp[i] = o;
}

// ---------------- transpose + cvt: in[R,C] fp32 -> out[C,R] bf16
__global__ __launch_bounds__(256) void transpose_cvt(const float* __restrict__ in,
                                                     unsigned short* __restrict__ outp,
                                                     int R, int C){
  __shared__ float tile[64][65];
  int r0 = blockIdx.y * 64, c0 = blockIdx.x * 64;
  int t = threadIdx.x;
  for (int i = t; i < 4096; i += 256){ int r = i >> 6, c = i & 63;
    tile[r][c] = in[(size_t)(r0 + r) * C + c0 + c]; }
  __syncthreads();
  for (int i = t; i < 4096; i += 256){ int c = i >> 6, r = i & 63;
    outp[(size_t)(c0 + c) * R + r0 + r] = f2bf(tile[r][c]); }
}

// ---------------- q softmax over d (in-place on qt[bh][d][n] bf16)
__global__ __launch_bounds__(256) void sm_q(unsigned short* __restrict__ qt){
  int bh = blockIdx.x >> 4;
  int n0 = (blockIdx.x & 15) << 8;
  int t = threadIdx.x;
  unsigned short* base = qt + (size_t)bh * 64 * SEQ + n0 + t;
  float v[64];
  float m = -1e30f;
#pragma unroll
  for (int d = 0; d < 64; d++){ v[d] = bf2f(base[d * SEQ]); m = fmaxf(m, v[d]); }
  m *= SCALE;
  float s = 0.f;
#pragma unroll
  for (int d = 0; d < 64; d++){ float e = __expf(v[d] * SCALE - m); v[d] = e; s += e; }
  float inv = 1.f / s;
#pragma unroll
  for (int d = 0; d < 64; d++) base[d * SEQ] = f2bf(v[d] * inv);
}

// ---------------- k softmax over n (in-place on kt[bh][e][n] bf16), one block per row
__global__ __launch_bounds__(256) void sm_k(unsigned short* __restrict__ kt){
  __shared__ float sred[8];
  int row = blockIdx.x;           // bh*64 + e
  int t = threadIdx.x, wave = t >> 6, lane = t & 63;
  unsigned short* base = kt + (size_t)row * SEQ + t * 16;
  float v[16];
#pragma unroll
  for (int i = 0; i < 16; i++) v[i] = bf2f(base[i]);
  float m = -1e30f;
#pragma unroll
  for (int i = 0; i < 16; i++) m = fmaxf(m, v[i]);
  for (int o = 32; o; o >>= 1) m = fmaxf(m, __shfl_down(m, o));
  if (!lane) sred[wave] = m;
  __syncthreads();
  m = fmaxf(fmaxf(sred[0], sred[1]), fmaxf(sred[2], sred[3]));
  float s = 0.f;
#pragma unroll
  for (int i = 0; i < 16; i++){ v[i] = __expf(v[i] - m); s += v[i]; }
  for (int o = 32; o; o >>= 1) s += __shfl_down(s, o);
  if (!lane) sred[4 + wave] = s;
  __syncthreads();
  s = (sred[4] + sred[5]) + (sred[6] + sred[7]);
  float inv = 1.f / s;
#pragma unroll
  for (int i = 0; i < 16; i++) base[i] = f2bf(v[i] * inv);
}

// ---------------- context[d,e] = sum_n qt[d,n]*kt[e,n] (per bh), K=4096
__global__ __launch_bounds__(256) void ctx_kernel(const unsigned short* __restrict__ qt,
                                                  const unsigned short* __restrict__ kt,
                                                  unsigned short* __restrict__ ctxb){
  __shared__ float red[4096];
  int bh = blockIdx.x;
  int t = threadIdx.x, wave = t >> 6, lane = t & 63, quad = lane >> 4, l16 = lane & 15;
  const unsigned short* qb = qt + (size_t)bh * 64 * SEQ;
  const unsigned short* kb = kt + (size_t)bh * 64 * SEQ;
  f4v acc[4][4];
#pragma unroll
  for (int i = 0; i < 4; i++)
#pragma unroll
    for (int j = 0; j < 4; j++) acc[i][j] = (f4v){0.f,0.f,0.f,0.f};
  int ns = wave * 1024;
  for (int n0 = ns; n0 < ns + 1024; n0 += 32){
    s8v af[4], bf[4];
#pragma unroll
    for (int mt = 0; mt < 4; mt++) af[mt] = *(const s8v*)&qb[(size_t)(mt*16 + l16) * SEQ + n0 + quad*8];
#pragma unroll
    for (int nt = 0; nt < 4; nt++) bf[nt] = *(const s8v*)&kb[(size_t)(nt*16 + l16) * SEQ + n0 + quad*8];
#pragma unroll
    for (int mt = 0; mt < 4; mt++)
#pragma unroll
      for (int nt = 0; nt < 4; nt++)
        acc[mt][nt] = __builtin_amdgcn_mfma_f32_16x16x32_bf16(af[mt], bf[nt], acc[mt][nt], 0, 0, 0);
  }
  for (int i = t; i < 4096; i += 256) red[i] = 0.f;
  __syncthreads();
  for (int w = 0; w < 4; w++){
    if (wave == w){
#pragma unroll
      for (int mt = 0; mt < 4; mt++)
#pragma unroll
        for (int nt = 0; nt < 4; nt++)
#pragma unroll
          for (int r = 0; r < 4; r++)
            red[(mt*16 + quad*4 + r) * 64 + nt*16 + l16] += acc[mt][nt][r];
    }
    __syncthreads();
  }
  unsigned short* cp = ctxb + (size_t)bh * 4096;
  for (int i = t; i < 4096; i += 256) cp[i] = f2bf(red[i]);
}

// ---------------- out[n,e] = sum_d v[n,d]*context[d,e] (K=64) -> obuf[b,n,h*64+e] bf16
__global__ __launch_bounds__(256) void outv_kernel(const unsigned short* __restrict__ vb,
                                                   const unsigned short* __restrict__ ctxb,
                                                   unsigned short* __restrict__ obuf){
  int bh = blockIdx.y; int b = bh >> 4, h = bh & 15;
  int n0 = blockIdx.x * 256;
  int t = threadIdx.x, wave = t >> 6, lane = t & 63, quad = lane >> 4, l16 = lane & 15;
  const unsigned short* cb = ctxb + (size_t)bh * 4096;
  s8v bfr[2][4];
#pragma unroll
  for (int kk = 0; kk < 2; kk++)
#pragma unroll
    for (int nt = 0; nt < 4; nt++){
      s8v v;
#pragma unroll
      for (int j = 0; j < 8; j++) v[j] = (short)cb[(kk*32 + quad*8 + j) * 64 + nt*16 + l16];
      bfr[kk][nt] = v;
    }
  f4v acc[4][4];
#pragma unroll
  for (int i = 0; i < 4; i++)
#pragma unroll
    for (int j = 0; j < 4; j++) acc[i][j] = (f4v){0.f,0.f,0.f,0.f};
  const unsigned short* vbase = vb + (size_t)(b * SEQ + n0 + wave * 64) * 1024 + h * 64;
  for (int kk = 0; kk < 2; kk++){
    s8v af[4];
#pragma unroll
    for (int mt = 0; mt < 4; mt++) af[mt] = *(const s8v*)&vbase[(size_t)(mt*16 + l16) * 1024 + kk*32 + quad*8];
#pragma unroll
    for (int mt = 0; mt < 4; mt++)
#pragma unroll
      for (int nt = 0; nt < 4; nt++)
        acc[mt][nt] = __builtin_amdgcn_mfma_f32_16x16x32_bf16(af[mt], bfr[kk][nt], acc[mt][nt], 0, 0, 0);
  }
  unsigned short* ob = obuf + (size_t)(b * SEQ + n0 + wave * 64) * 1024 + h * 64;
#pragma unroll
  for (int mt = 0; mt < 4; mt++)
#pragma unroll
    for (int nt = 0; nt < 4; nt++)
#pragma unroll
      for (int r = 0; r < 4; r++)
        ob[(size_t)(mt*16 + quad*4 + r) * 1024 + nt*16 + l16] = f2bf(acc[mt][nt][r]);
}

extern "C" void kernel_launch(void* const* d_in, const int* in_sizes, int n_in,
                              void* d_out, int out_size, void* d_ws, size_t ws_size,
                              hipStream_t stream) {
  const float* x     = (const float*)d_in[0];  // [4,4096,1024]
  const float* w_qkv = (const float*)d_in[1];  // [1024,3072]
  const float* w_out = (const float*)d_in[2];  // [1024,1024]
  const float* b_out = (const float*)d_in[3];  // [1024]
  float* out = (float*)d_out;                  // [4,4096,1024] fp32

  const int M = 4 * SEQ;  // 16384

  // x in bf16 lives in the (dead-until-final-GEMM) output buffer: 32 MiB of 64 MiB
  unsigned short* xb = (unsigned short*)d_out;

  char* wp = (char*)d_ws;
  size_t off = 0;
  auto nxt = [&](size_t bytes) -> char* {
    char* p = wp + off;
    off += (bytes + 255) & ~(size_t)255;
    return p;
  };
  unsigned short* wqkvT = (unsigned short*)nxt((size_t)3072 * 1024 * 2);   // 6 MiB
  unsigned short* woT   = (unsigned short*)nxt((size_t)1024 * 1024 * 2);   // 2 MiB
  unsigned short* qt    = (unsigned short*)nxt((size_t)64 * 64 * SEQ * 2); // 32 MiB (reused as obuf)
  unsigned short* kt    = (unsigned short*)nxt((size_t)64 * 64 * SEQ * 2); // 32 MiB
  unsigned short* vb    = (unsigned short*)nxt((size_t)M * 1024 * 2);      // 32 MiB
  unsigned short* ctxb  = (unsigned short*)nxt((size_t)64 * 4096 * 2);     // 0.5 MiB
  unsigned short* obuf  = qt;  // qt dead after ctx_kernel

  // 1. converts
  cvt_f32_bf16<<<(M * 1024) / 4 / 256, 256, 0, stream>>>((const float4*)x, (ushort4*)xb);
  transpose_cvt<<<dim3(3072 / 64, 1024 / 64), 256, 0, stream>>>(w_qkv, wqkvT, 1024, 3072);
  transpose_cvt<<<dim3(1024 / 64, 1024 / 64), 256, 0, stream>>>(w_out, woT, 1024, 1024);

  // 2. fused qkv GEMM -> qt (head-T), kt (head-T), vb
  qkv_gemm<<<dim3(3072 / 128, M / 128), 256, 0, stream>>>(xb, wqkvT, qt, kt, vb);

  // 3. in-place softmaxes
  sm_q<<<64 * (SEQ / 256), 256, 0, stream>>>(qt);
  sm_k<<<64 * 64, 256, 0, stream>>>(kt);

  // 4. context = q^T k (per bh)
  ctx_kernel<<<64, 256, 0, stream>>>(qt, kt, ctxb);

  // 5. out_attn = v * context -> obuf (aliases qt)
  outv_kernel<<<dim3(SEQ / 256, 64), 256, 0, stream>>>(vb, ctxb, obuf);

  // 6. final projection + bias -> fp32 out (overwrites xb region)
  gemm_bt<<<dim3(1024 / 128, M / 128), 256, 0, stream>>>(obuf, woT, out, b_out, M, 1024, 1024);
}

// Round 3
// 395.862 us; speedup vs baseline: 1.0746x; 1.0746x over previous
//
#include <hip/hip_runtime.h>
#include <hip/hip_bf16.h>

#define SEQ    4096
#define SCALE  0.125f

typedef __attribute__((ext_vector_type(8))) short s8v;
typedef __attribute__((ext_vector_type(4))) float f4v;

__device__ __forceinline__ unsigned short f2bf(float f){
  unsigned int u = __builtin_bit_cast(unsigned int, f);
  u += 0x7FFFu + ((u >> 16) & 1u);
  return (unsigned short)(u >> 16);
}
__device__ __forceinline__ float bf2f(unsigned short s){
  unsigned int u = ((unsigned int)s) << 16;
  return __builtin_bit_cast(float, u);
}

typedef const __attribute__((address_space(1))) unsigned int gl_uint;
typedef __attribute__((address_space(3))) unsigned int lds_uint;

__device__ __forceinline__ void gload_lds16(const unsigned short* g, unsigned short* l){
  __builtin_amdgcn_global_load_lds((gl_uint*)g, (lds_uint*)l, 16, 0, 0);
}

// ---------------- qkv GEMM (stripe-swizzled, fused q-softmax):
// cols 0..1023    -> qt[bh][d][n] bf16, SOFTMAXED over d (fp32 logits)
// cols 1024..2047 -> kt[bh][e][n] bf16 (raw logits)
// cols 2048..3071 -> vb[row][col-2048] bf16
__global__ __launch_bounds__(256) void qkv_gemm(
    const unsigned short* __restrict__ A,
    const unsigned short* __restrict__ Bt,
    unsigned short* __restrict__ qt,
    unsigned short* __restrict__ kt,
    unsigned short* __restrict__ vb)
{
  __shared__ unsigned short sA[128*32];
  __shared__ unsigned short sB[128*32];
  const int K = 1024;
  const int tid  = threadIdx.x;
  const int wave = tid >> 6, lane = tid & 63;
  const int quad = lane >> 4, l16 = lane & 15;
  // stripe swizzle: 16 row-blocks x 24 col-blocks per stripe
  const int bid = blockIdx.x;
  const int per = 16 * 24;
  const int st = bid / per, rr = bid % per;
  const int bm = (st * 16 + (rr % 16)) * 128;
  const int bn = (rr / 16) * 128;
  const int wm = (wave >> 1) * 64, wn = (wave & 1) * 64;

  f4v acc[4][4];
#pragma unroll
  for (int i = 0; i < 4; i++)
#pragma unroll
    for (int j = 0; j < 4; j++) acc[i][j] = (f4v){0.f,0.f,0.f,0.f};

  const unsigned short* ap = A  + (size_t)(bm + (tid >> 2)) * K + (tid & 3) * 8;
  const unsigned short* bp = Bt + (size_t)(bn + (tid >> 2)) * K + (tid & 3) * 8;
  unsigned short* sAw = sA + wave * 512;
  unsigned short* sBw = sB + wave * 512;

  for (int k0 = 0; k0 < K; k0 += 32){
    __syncthreads();
    gload_lds16(ap + k0,                    sAw);
    gload_lds16(ap + (size_t)64 * K + k0,   sAw + 2048);
    gload_lds16(bp + k0,                    sBw);
    gload_lds16(bp + (size_t)64 * K + k0,   sBw + 2048);
    __syncthreads();
    s8v af[4], bf[4];
#pragma unroll
    for (int mt = 0; mt < 4; mt++) af[mt] = *(const s8v*)&sA[(wm + mt*16 + l16)*32 + quad*8];
#pragma unroll
    for (int nt = 0; nt < 4; nt++) bf[nt] = *(const s8v*)&sB[(wn + nt*16 + l16)*32 + quad*8];
#pragma unroll
    for (int mt = 0; mt < 4; mt++)
#pragma unroll
      for (int nt = 0; nt < 4; nt++)
        acc[mt][nt] = __builtin_amdgcn_mfma_f32_16x16x32_bf16(af[mt], bf[nt], acc[mt][nt], 0, 0, 0);
  }

  const int colbase = bn + wn;           // 64-aligned -> one head per wave tile
  const int sec = colbase >> 10;         // 0=q 1=k 2=v (wave-uniform)

  if (sec == 2){
#pragma unroll
    for (int nt = 0; nt < 4; nt++){
      int vc = colbase + nt*16 + l16 - 2048;
#pragma unroll
      for (int mt = 0; mt < 4; mt++){
        int row = bm + wm + mt*16 + quad*4;
#pragma unroll
        for (int r = 0; r < 4; r++)
          vb[(size_t)(row + r) * 1024 + vc] = f2bf(acc[mt][nt][r]);
      }
    }
    return;
  }

  if (sec == 0){
    // fused softmax over d (the wave's 64 cols = one full head)
#pragma unroll
    for (int mt = 0; mt < 4; mt++){
#pragma unroll
      for (int r = 0; r < 4; r++){
        float m = fmaxf(fmaxf(acc[mt][0][r], acc[mt][1][r]),
                        fmaxf(acc[mt][2][r], acc[mt][3][r]));
        for (int off = 8; off; off >>= 1) m = fmaxf(m, __shfl_xor(m, off));
        m *= SCALE;
        float e0 = __expf(acc[mt][0][r] * SCALE - m);
        float e1 = __expf(acc[mt][1][r] * SCALE - m);
        float e2 = __expf(acc[mt][2][r] * SCALE - m);
        float e3 = __expf(acc[mt][3][r] * SCALE - m);
        float s = (e0 + e1) + (e2 + e3);
        for (int off = 8; off; off >>= 1) s += __shfl_xor(s, off);
        float inv = 1.f / s;
        acc[mt][0][r] = e0 * inv; acc[mt][1][r] = e1 * inv;
        acc[mt][2][r] = e2 * inv; acc[mt][3][r] = e3 * inv;
      }
    }
  }

  unsigned short* dst = sec ? kt : qt;
#pragma unroll
  for (int nt = 0; nt < 4; nt++){
    int col = colbase + nt*16 + l16;
    int h = (col >> 6) & 15;
    int de = col & 63;
#pragma unroll
    for (int mt = 0; mt < 4; mt++){
      int row = bm + wm + mt*16 + quad*4;
      int bb = row >> 12;
      int nl = row & 4095;
      ushort4 o;
      o.x = f2bf(acc[mt][nt][0]); o.y = f2bf(acc[mt][nt][1]);
      o.z = f2bf(acc[mt][nt][2]); o.w = f2bf(acc[mt][nt][3]);
      *(ushort4*)&dst[(((size_t)bb * 16 + h) * 64 + de) * SEQ + nl] = o;
    }
  }
}

// ---------------- final batched GEMM: out[b] = vb[b] @ ctx2t[b]^T + bias, fp32
__global__ __launch_bounds__(256) void gemm_final(
    const unsigned short* __restrict__ A,
    const unsigned short* __restrict__ C2t,
    float* __restrict__ Cf,
    const float* __restrict__ bias)
{
  __shared__ unsigned short sA[128*32];
  __shared__ unsigned short sB[128*32];
  const int K = 1024;
  const int tid  = threadIdx.x;
  const int wave = tid >> 6, lane = tid & 63;
  const int quad = lane >> 4, l16 = lane & 15;
  // stripe swizzle: 16 row-blocks x 8 col-blocks
  const int bid = blockIdx.x;
  const int per = 16 * 8;
  const int st = bid / per, rr = bid % per;
  const int by = st * 16 + (rr % 16);
  const int bm = by * 128;
  const int bn = (rr / 16) * 128;
  const int b  = by >> 5;   // 32 row-blocks per batch
  const unsigned short* Bt = C2t + (size_t)b * 1024 * 1024;
  const int wm = (wave >> 1) * 64, wn = (wave & 1) * 64;

  f4v acc[4][4];
#pragma unroll
  for (int i = 0; i < 4; i++)
#pragma unroll
    for (int j = 0; j < 4; j++) acc[i][j] = (f4v){0.f,0.f,0.f,0.f};

  const unsigned short* ap = A  + (size_t)(bm + (tid >> 2)) * K + (tid & 3) * 8;
  const unsigned short* bp = Bt + (size_t)(bn + (tid >> 2)) * K + (tid & 3) * 8;
  unsigned short* sAw = sA + wave * 512;
  unsigned short* sBw = sB + wave * 512;

  for (int k0 = 0; k0 < K; k0 += 32){
    __syncthreads();
    gload_lds16(ap + k0,                    sAw);
    gload_lds16(ap + (size_t)64 * K + k0,   sAw + 2048);
    gload_lds16(bp + k0,                    sBw);
    gload_lds16(bp + (size_t)64 * K + k0,   sBw + 2048);
    __syncthreads();
    s8v af[4], bf[4];
#pragma unroll
    for (int mt = 0; mt < 4; mt++) af[mt] = *(const s8v*)&sA[(wm + mt*16 + l16)*32 + quad*8];
#pragma unroll
    for (int nt = 0; nt < 4; nt++) bf[nt] = *(const s8v*)&sB[(wn + nt*16 + l16)*32 + quad*8];
#pragma unroll
    for (int mt = 0; mt < 4; mt++)
#pragma unroll
      for (int nt = 0; nt < 4; nt++)
        acc[mt][nt] = __builtin_amdgcn_mfma_f32_16x16x32_bf16(af[mt], bf[nt], acc[mt][nt], 0, 0, 0);
  }

#pragma unroll
  for (int nt = 0; nt < 4; nt++){
    int col = bn + wn + nt*16 + l16;
    float bv = bias[col];
#pragma unroll
    for (int mt = 0; mt < 4; mt++){
      int row = bm + wm + mt*16 + quad*4;
#pragma unroll
      for (int r = 0; r < 4; r++)
        Cf[(size_t)(row + r) * 1024 + col] = acc[mt][nt][r] + bv;
    }
  }
}

// ---------------- fp32 -> bf16 elementwise (4/thread)
__global__ void cvt_f32_bf16(const float4* __restrict__ in, ushort4* __restrict__ outp){
  int i = blockIdx.x * 256 + threadIdx.x;
  float4 v = in[i];
  ushort4 o;
  o.x = f2bf(v.x); o.y = f2bf(v.y); o.z = f2bf(v.z); o.w = f2bf(v.w);
  outp[i] = o;
}

// ---------------- transpose + cvt: in[R,C] fp32 -> out[C,R] bf16
__global__ __launch_bounds__(256) void transpose_cvt(const float* __restrict__ in,
                                                     unsigned short* __restrict__ outp,
                                                     int R, int C){
  __shared__ float tile[64][65];
  int r0 = blockIdx.y * 64, c0 = blockIdx.x * 64;
  int t = threadIdx.x;
  for (int i = t; i < 4096; i += 256){ int r = i >> 6, c = i & 63;
    tile[r][c] = in[(size_t)(r0 + r) * C + c0 + c]; }
  __syncthreads();
  for (int i = t; i < 4096; i += 256){ int c = i >> 6, r = i & 63;
    outp[(size_t)(c0 + c) * R + r0 + r] = f2bf(tile[r][c]); }
}

// ---------------- k softmax over n (in-place on kt[bh][e][n] bf16), one block per row
__global__ __launch_bounds__(256) void sm_k(unsigned short* __restrict__ kt){
  __shared__ float sred[8];
  int row = blockIdx.x;           // bh*64 + e
  int t = threadIdx.x, wave = t >> 6, lane = t & 63;
  unsigned short* base = kt + (size_t)row * SEQ + t * 16;
  float v[16];
#pragma unroll
  for (int i = 0; i < 16; i++) v[i] = bf2f(base[i]);
  float m = -1e30f;
#pragma unroll
  for (int i = 0; i < 16; i++) m = fmaxf(m, v[i]);
  for (int o = 32; o; o >>= 1) m = fmaxf(m, __shfl_down(m, o));
  if (!lane) sred[wave] = m;
  __syncthreads();
  m = fmaxf(fmaxf(sred[0], sred[1]), fmaxf(sred[2], sred[3]));
  float s = 0.f;
#pragma unroll
  for (int i = 0; i < 16; i++){ v[i] = __expf(v[i] - m); s += v[i]; }
  for (int o = 32; o; o >>= 1) s += __shfl_down(s, o);
  if (!lane) sred[4 + wave] = s;
  __syncthreads();
  s = (sred[4] + sred[5]) + (sred[6] + sred[7]);
  float inv = 1.f / s;
#pragma unroll
  for (int i = 0; i < 16; i++) base[i] = f2bf(v[i] * inv);
}

// ---------------- ctx partial: ctxp[bh*4+chunk][d*64+e] = sum_{n in chunk} qt[d,n] kt[e,n]
__global__ __launch_bounds__(256) void ctx_partial(const unsigned short* __restrict__ qt,
                                                   const unsigned short* __restrict__ kt,
                                                   float* __restrict__ ctxp){
  __shared__ float red[4096];
  int bh = blockIdx.x >> 2, ch = blockIdx.x & 3;
  int t = threadIdx.x, wave = t >> 6, lane = t & 63, quad = lane >> 4, l16 = lane & 15;
  const unsigned short* qb = qt + (size_t)bh * 64 * SEQ;
  const unsigned short* kb = kt + (size_t)bh * 64 * SEQ;
  f4v acc[4][4];
#pragma unroll
  for (int i = 0; i < 4; i++)
#pragma unroll
    for (int j = 0; j < 4; j++) acc[i][j] = (f4v){0.f,0.f,0.f,0.f};
  int ns = ch * 1024 + wave * 256;
  for (int n0 = ns; n0 < ns + 256; n0 += 32){
    s8v af[4], bf[4];
#pragma unroll
    for (int mt = 0; mt < 4; mt++) af[mt] = *(const s8v*)&qb[(size_t)(mt*16 + l16) * SEQ + n0 + quad*8];
#pragma unroll
    for (int nt = 0; nt < 4; nt++) bf[nt] = *(const s8v*)&kb[(size_t)(nt*16 + l16) * SEQ + n0 + quad*8];
#pragma unroll
    for (int mt = 0; mt < 4; mt++)
#pragma unroll
      for (int nt = 0; nt < 4; nt++)
        acc[mt][nt] = __builtin_amdgcn_mfma_f32_16x16x32_bf16(af[mt], bf[nt], acc[mt][nt], 0, 0, 0);
  }
  for (int i = t; i < 4096; i += 256) red[i] = 0.f;
  __syncthreads();
  for (int w = 0; w < 4; w++){
    if (wave == w){
#pragma unroll
      for (int mt = 0; mt < 4; mt++)
#pragma unroll
        for (int nt = 0; nt < 4; nt++)
#pragma unroll
          for (int r = 0; r < 4; r++)
            red[(mt*16 + quad*4 + r) * 64 + nt*16 + l16] += acc[mt][nt][r];
    }
    __syncthreads();
  }
  float* cp = ctxp + (size_t)blockIdx.x * 4096;
  for (int i = t; i < 4096; i += 256) cp[i] = red[i];
}

// ---------------- ctx2t[b][f][h*64+d] = sum_e ctx[b,h][d][e] * w_out[h*64+e][f]   (bf16 out)
__global__ __launch_bounds__(256) void ctx2_kernel(const float* __restrict__ ctxp,
                                                   const float* __restrict__ w_out,
                                                   unsigned short* __restrict__ ctx2t){
  __shared__ float ctxs[4096];
  int bh = blockIdx.x >> 4, fc = blockIdx.x & 15;
  int b = bh >> 4, h = bh & 15;
  int t = threadIdx.x;
  int fl = t & 63, dg = t >> 6;      // dg uniform per wave -> LDS broadcast
  int f = fc * 64 + fl;
  for (int i = t; i < 4096; i += 256){
    const float* p = ctxp + (size_t)bh * 4 * 4096 + i;
    ctxs[i] = (p[0] + p[4096]) + (p[8192] + p[12288]);
  }
  __syncthreads();
  float acc[16];
#pragma unroll
  for (int i = 0; i < 16; i++) acc[i] = 0.f;
  for (int e = 0; e < 64; e++){
    float w = w_out[(size_t)(h * 64 + e) * 1024 + f];
#pragma unroll
    for (int dd = 0; dd < 16; dd++)
      acc[dd] += ctxs[(dg * 16 + dd) * 64 + e] * w;
  }
  unsigned short* op = ctx2t + ((size_t)b * 1024 + f) * 1024 + h * 64 + dg * 16;
#pragma unroll
  for (int g = 0; g < 4; g++){
    ushort4 o;
    o.x = f2bf(acc[g*4+0]); o.y = f2bf(acc[g*4+1]);
    o.z = f2bf(acc[g*4+2]); o.w = f2bf(acc[g*4+3]);
    *(ushort4*)&op[g*4] = o;
  }
}

extern "C" void kernel_launch(void* const* d_in, const int* in_sizes, int n_in,
                              void* d_out, int out_size, void* d_ws, size_t ws_size,
                              hipStream_t stream) {
  const float* x     = (const float*)d_in[0];  // [4,4096,1024]
  const float* w_qkv = (const float*)d_in[1];  // [1024,3072]
  const float* w_out = (const float*)d_in[2];  // [1024,1024]
  const float* b_out = (const float*)d_in[3];  // [1024]
  float* out = (float*)d_out;                  // [4,4096,1024] fp32

  const int M = 4 * SEQ;  // 16384

  // x bf16 lives in d_out's first 32 MiB (dead before gemm_final writes out)
  unsigned short* xb = (unsigned short*)d_out;

  char* wp = (char*)d_ws;
  size_t off = 0;
  auto nxt = [&](size_t bytes) -> char* {
    char* p = wp + off;
    off += (bytes + 255) & ~(size_t)255;
    return p;
  };
  unsigned short* wqkvT = (unsigned short*)nxt((size_t)3072 * 1024 * 2);   // 6 MiB
  unsigned short* qt    = (unsigned short*)nxt((size_t)64 * 64 * SEQ * 2); // 32 MiB
  unsigned short* kt    = (unsigned short*)nxt((size_t)64 * 64 * SEQ * 2); // 32 MiB
  unsigned short* vb    = (unsigned short*)nxt((size_t)M * 1024 * 2);      // 32 MiB
  float*          ctxp  = (float*)wqkvT;       // 4 MiB, aliases wqkvT (dead after qkv_gemm)
  unsigned short* ctx2t = qt;                  // 8 MiB, aliases qt (dead after ctx_partial)

  // 1. converts
  cvt_f32_bf16<<<(M * 1024) / 4 / 256, 256, 0, stream>>>((const float4*)x, (ushort4*)xb);
  transpose_cvt<<<dim3(3072 / 64, 1024 / 64), 256, 0, stream>>>(w_qkv, wqkvT, 1024, 3072);

  // 2. fused qkv GEMM (+q softmax) -> qt, kt, vb   [swizzled 1D grid]
  qkv_gemm<<<(3072 / 128) * (M / 128), 256, 0, stream>>>(xb, wqkvT, qt, kt, vb);

  // 3. k softmax in-place
  sm_k<<<64 * 64, 256, 0, stream>>>(kt);

  // 4. context partials (fp32), 256 blocks
  ctx_partial<<<64 * 4, 256, 0, stream>>>(qt, kt, ctxp);

  // 5. ctx2t[b][f][hd] = (ctx @ w_out_h)^T  (fp32 accumulate, bf16 out)
  ctx2_kernel<<<64 * 16, 256, 0, stream>>>(ctxp, w_out, ctx2t);

  // 6. final batched GEMM: out[b] = vb[b] @ ctx2t[b]^T + bias  [swizzled 1D grid]
  gemm_final<<<(1024 / 128) * (M / 128), 256, 0, stream>>>(vb, ctx2t, out, b_out);
}